// Round 14
// baseline (489.483 us; speedup 1.0000x reference)
//
#include <hip/hip_runtime.h>
#include <hip/hip_bf16.h>

#define N_TOK 8192
#define DDIM 1024
#define HDIM 4096
#define NEXP 8
#define TOPK 2
#define NK (N_TOK*TOPK)
#define BM 256
#define BK 64
#define MAXT 72    // 16384/256 + 8 pad tiles

typedef __hip_bfloat16 bf16;
typedef __attribute__((ext_vector_type(8))) short bf16x8;
typedef __attribute__((ext_vector_type(4))) float f32x4;

__device__ __forceinline__ void gload16(const void* g, void* lds) {
  auto l = (__attribute__((address_space(3))) unsigned int*)(unsigned int)(unsigned long long)lds;
  auto gg = (const __attribute__((address_space(1))) unsigned int*)(unsigned long long)g;
  __builtin_amdgcn_global_load_lds(gg, l, 16, 0, 0);
}

// ---- fused router: count + padded scan + scatter + pad-fill, one block ----
__global__ void k_router(const int* __restrict__ idx, int stride,
                         int* __restrict__ offp, int* __restrict__ texp,
                         int* __restrict__ tok, int* __restrict__ pos) {
  __shared__ int cnt[NEXP], so[NEXP + 1], off2[NEXP], scnt[NEXP];
  int tid = threadIdx.x;
  if (tid < NEXP) cnt[tid] = 0;
  __syncthreads();
  for (int r = tid; r < NK; r += blockDim.x) {
    int e = idx[r * stride];
    e = min(max(e, 0), NEXP - 1);
    atomicAdd(&cnt[e], 1);
  }
  __syncthreads();
  if (tid == 0) {
    int cum = 0;
    for (int e = 0; e < NEXP; e++) {
      so[e] = cum;
      cum += ((cnt[e] + BM - 1) / BM) * BM;
    }
    so[NEXP] = cum;
    for (int e = 0; e <= NEXP; e++) offp[e] = so[e];
  }
  __syncthreads();
  if (tid < NEXP) { off2[tid] = so[tid]; scnt[tid] = cnt[tid]; }
  __syncthreads();
  for (int r = tid; r < NK; r += blockDim.x) {
    int e = idx[r * stride];
    e = min(max(e, 0), NEXP - 1);
    int p = atomicAdd(&off2[e], 1);
    tok[p] = r >> 1;
    pos[r] = p;
  }
  int total_tiles = so[NEXP] / BM;
  for (int t = tid; t < MAXT; t += blockDim.x) {
    int e = -1;
    if (t < total_tiles) {
      for (int q = 0; q < NEXP; q++)
        if (t * BM >= so[q] && t * BM < so[q + 1]) e = q;
    }
    texp[t] = e;
  }
  for (int e = 0; e < NEXP; e++) {
    int start = so[e] + scnt[e], end = so[e + 1];
    for (int i = start + tid; i < end; i += blockDim.x) tok[i] = 0;
  }
}

// ---- fp32 -> bf16 convert of X ----
__global__ void k_cvt_x(const float* __restrict__ x, bf16* __restrict__ xb) {
  int i = blockIdx.x * blockDim.x + threadIdx.x;   // over N*D/8
  if (i >= N_TOK * DDIM / 8) return;
  float4 a = ((const float4*)x)[(size_t)i * 2];
  float4 b = ((const float4*)x)[(size_t)i * 2 + 1];
  union { bf16 h[8]; uint4 v; } u;
  u.h[0] = __float2bfloat16(a.x); u.h[1] = __float2bfloat16(a.y);
  u.h[2] = __float2bfloat16(a.z); u.h[3] = __float2bfloat16(a.w);
  u.h[4] = __float2bfloat16(b.x); u.h[5] = __float2bfloat16(b.y);
  u.h[6] = __float2bfloat16(b.z); u.h[7] = __float2bfloat16(b.w);
  *(uint4*)&xb[(size_t)i * 8] = u.v;
}

// [E][R][C] fp32 -> [E][C][R] bf16. Tile 32R x 64C; 16B stores.
__global__ void k_transpose(const float* __restrict__ in, bf16* __restrict__ out,
                            int R, int C) {
  __shared__ float t[32][65];
  size_t ebase = (size_t)blockIdx.z * R * C;
  int r0 = blockIdx.y * 32, c0 = blockIdx.x * 64;
  int tid = threadIdx.x;
  {
    int lr = tid >> 3, lc = (tid & 7) * 8;
    const float4* src = (const float4*)&in[ebase + (size_t)(r0 + lr) * C + c0 + lc];
    float4 a = src[0], b = src[1];
    t[lr][lc + 0] = a.x; t[lr][lc + 1] = a.y; t[lr][lc + 2] = a.z; t[lr][lc + 3] = a.w;
    t[lr][lc + 4] = b.x; t[lr][lc + 5] = b.y; t[lr][lc + 6] = b.z; t[lr][lc + 7] = b.w;
  }
  __syncthreads();
  {
    int sc = tid >> 2, sr = (tid & 3) * 8;
    union { bf16 h[8]; uint4 v; } u;
#pragma unroll
    for (int j = 0; j < 8; j++) u.h[j] = __float2bfloat16(t[sr + j][sc]);
    *(uint4*)&out[ebase + (size_t)(c0 + sc) * R + r0 + sr] = u.v;
  }
}

// ---- grouped GEMM: 256x256 tile, BK=64, 8 waves (2Mx4N, 128x64/wave),
//      m201-style 8-phase schedule, 2 K-tiles/iter, vmcnt(4) at P3/P7
//      (ledger-derived), XOR-8 LDS swizzle both sides. 128 KiB LDS, 1 blk/CU. ----
// MODE 0: Xb(gathered via tok) @ W1t -> hbuf bf16 (+bias, ReLU), slice rows.
// MODE 1: hbuf @ W2t -> ybuf bf16 (+bias), global rows.
template<int MODE>
__global__ __launch_bounds__(512, 2) void k_gemm(
    const bf16* __restrict__ A, const bf16* __restrict__ Bt,
    const float* __restrict__ bias, const int* __restrict__ texp,
    const int* __restrict__ tok, int tile_base, void* __restrict__ Cout)
{
  constexpr int KT    = MODE ? HDIM : DDIM;   // 4096 : 1024
  constexpr int NCOL  = MODE ? DDIM : HDIM;
  constexpr int GX    = NCOL / 256;           // 4 : 16
  constexpr int NT    = KT / BK;              // 64 : 16
  constexpr int NITER = NT / 2;
  constexpr int BUFB  = 65536;                // 64 KB per buffer (A 32K + B 32K)

  // bijective XCD-aware swizzle (m204)
  int nwg = gridDim.x, orig = blockIdx.x;
  int q8 = nwg >> 3, r8 = nwg & 7;
  int xcd = orig & 7, jj0 = orig >> 3;
  int w = (xcd < r8 ? xcd * (q8 + 1) : r8 * (q8 + 1) + (xcd - r8) * q8) + jj0;
  int tn = w % GX;
  int tmr = w / GX;
  int tm = tile_base + tmr;
  int e = texp[tm];
  if (e < 0) return;

  int tid = threadIdx.x, lane = tid & 63, wid = tid >> 6;
  int wm = wid >> 2, wn = wid & 3;            // 2M x 4N waves, 128x64 each
  int lr = lane & 15, kg = lane >> 4;

  __shared__ __align__(16) char lds[2 * BUFB];   // 128 KiB

  // staging offsets (elements); source XOR-8 chunk swizzle c ^= (row&7)
  unsigned aoff[2][2], boff[2][2];
#pragma unroll
  for (int h = 0; h < 2; ++h) {
#pragma unroll
    for (int it = 0; it < 2; ++it) {
      int idx = it * 512 + tid, rl = idx >> 3, c = idx & 7;
      int ch = c ^ (rl & 7);
      int arow = MODE ? (tmr * BM + h * 128 + rl) : tok[tm * BM + h * 128 + rl];
      aoff[h][it] = (unsigned)(arow * KT + ch * 8);
      boff[h][it] = (unsigned)((e * NCOL + tn * 256 + h * 128 + rl) * KT + ch * 8);
    }
  }

  auto stA = [&](int kt, int h) {
    char* dst = lds + (kt & 1) * BUFB + h * 16384;
    gload16(A + (size_t)aoff[h][0] + kt * BK, dst + tid * 16);
    gload16(A + (size_t)aoff[h][1] + kt * BK, dst + 8192 + tid * 16);
  };
  auto stB = [&](int kt, int h) {
    char* dst = lds + (kt & 1) * BUFB + 32768 + h * 16384;
    gload16(Bt + (size_t)boff[h][0] + kt * BK, dst + tid * 16);
    gload16(Bt + (size_t)boff[h][1] + kt * BK, dst + 8192 + tid * 16);
  };

  f32x4 acc[8][4];
#pragma unroll
  for (int i = 0; i < 8; i++)
#pragma unroll
    for (int j = 0; j < 4; j++) acc[i][j] = (f32x4){0.f, 0.f, 0.f, 0.f};

  bf16x8 bv[8];
  auto readB8 = [&](const char* buf) {
    const char* bb = buf + 32768;
#pragma unroll
    for (int ni = 0; ni < 4; ++ni)
#pragma unroll
      for (int kh = 0; kh < 2; ++kh) {
        int r = wn * 64 + ni * 16 + lr;
        int ck = (kh * 4 + kg) ^ (r & 7);
        bv[ni * 2 + kh] = *(const bf16x8*)(bb + r * 128 + ck * 16);
      }
  };
  auto readA4 = [&](const char* buf, int q, bf16x8* av) {
#pragma unroll
    for (int g = 0; g < 2; ++g)
#pragma unroll
      for (int kh = 0; kh < 2; ++kh) {
        int r = wm * 128 + (q * 2 + g) * 16 + lr;
        int ck = (kh * 4 + kg) ^ (r & 7);
        av[g * 2 + kh] = *(const bf16x8*)(buf + r * 128 + ck * 16);
      }
  };
  auto mfmaQ = [&](int q, bf16x8* av) {
    __builtin_amdgcn_s_setprio(1);
#pragma unroll
    for (int g = 0; g < 2; ++g)
#pragma unroll
      for (int ni = 0; ni < 4; ++ni)
#pragma unroll
        for (int kh = 0; kh < 2; ++kh)
          acc[q * 2 + g][ni] = __builtin_amdgcn_mfma_f32_16x16x32_bf16(
              av[g * 2 + kh], bv[ni * 2 + kh], acc[q * 2 + g][ni], 0, 0, 0);
    __builtin_amdgcn_s_setprio(0);
  };

#define BAR()    __builtin_amdgcn_s_barrier()
#define LGKM0()  asm volatile("s_waitcnt lgkmcnt(0)" ::: "memory")
#define LGKM8()  asm volatile("s_waitcnt lgkmcnt(8)" ::: "memory")

  // prologue: T0 complete + T1.B in flight; vmcnt(4) publishes T0.
  stA(0, 0); stA(0, 1); stB(0, 0); stB(0, 1);
  stB(1, 0); stB(1, 1);
  asm volatile("s_waitcnt vmcnt(4)" ::: "memory");
  BAR();

  const char* b0 = lds;
  const char* b1 = lds + BUFB;

#pragma unroll 1
  for (int i = 0; i < NITER; ++i) {
    int t = 2 * i;
    bool last = (i == NITER - 1);
    bf16x8 av[4];

    // P0: reads(buf0: B all + A q0) || stage A(t+1)lo -> buf1
    readB8(b0); readA4(b0, 0, av);
    stA(t + 1, 0);
    LGKM8();
    BAR(); LGKM0(); mfmaQ(0, av); BAR();

    // P1: A q1 || stage A(t+1)hi
    readA4(b0, 1, av); stA(t + 1, 1);
    BAR(); LGKM0(); mfmaQ(1, av); BAR();

    // P2: A q2 || stage B(t+2)lo -> buf0.B (free after P0)
    readA4(b0, 2, av); if (!last) stB(t + 2, 0);
    BAR(); LGKM0(); mfmaQ(2, av); BAR();

    // P3: A q3 || stage B(t+2)hi; vmcnt(4) publishes T(t+1)
    readA4(b0, 3, av); if (!last) stB(t + 2, 1);
    if (last) { asm volatile("s_waitcnt vmcnt(0)" ::: "memory"); }
    else      { asm volatile("s_waitcnt vmcnt(4)" ::: "memory"); }
    BAR(); LGKM0(); mfmaQ(3, av); BAR();

    // P4: reads(buf1: B all + A q0) || stage A(t+2)lo -> buf0.A (free after P3)
    readB8(b1); readA4(b1, 0, av); if (!last) stA(t + 2, 0);
    LGKM8();
    BAR(); LGKM0(); mfmaQ(0, av); BAR();

    // P5: A q1 || stage A(t+2)hi
    readA4(b1, 1, av); if (!last) stA(t + 2, 1);
    BAR(); LGKM0(); mfmaQ(1, av); BAR();

    // P6: A q2 || stage B(t+3)lo -> buf1.B (free after P4)
    readA4(b1, 2, av); if (!last) stB(t + 3, 0);
    BAR(); LGKM0(); mfmaQ(2, av); BAR();

    // P7: A q3 || stage B(t+3)hi; vmcnt(4) publishes T(t+2)
    readA4(b1, 3, av); if (!last) stB(t + 3, 1);
    if (!last) { asm volatile("s_waitcnt vmcnt(4)" ::: "memory"); }
    BAR(); LGKM0(); mfmaQ(3, av); BAR();
  }

  // epilogue (C/D map m89)
  const float* be = bias + (size_t)e * NCOL;
  int crow0 = (MODE ? tm : tmr) * BM;
#pragma unroll
  for (int ni = 0; ni < 4; ++ni) {
    int n = tn * 256 + wn * 64 + ni * 16 + lr;
    float bvv = be[n];
#pragma unroll
    for (int mi = 0; mi < 8; ++mi) {
#pragma unroll
      for (int j = 0; j < 4; j++) {
        int mrow = wm * 128 + mi * 16 + kg * 4 + j;
        float v = acc[mi][ni][j] + bvv;
        if (MODE == 0) v = fmaxf(v, 0.f);
        ((bf16*)Cout)[(size_t)(crow0 + mrow) * NCOL + n] = __float2bfloat16(v);
      }
    }
  }
#undef BAR
#undef LGKM0
#undef LGKM8
}

// ---- combine (bf16 y) ----
__global__ void k_combine(const bf16* __restrict__ y, const float* __restrict__ prob,
                          const int* __restrict__ pos, float* __restrict__ out) {
  int gid = blockIdx.x * blockDim.x + threadIdx.x;  // over N*D/8
  if (gid >= N_TOK * DDIM / 8) return;
  int n = gid >> 7;          // DDIM/8 = 128
  int d8 = gid & 127;
  int r0 = pos[2 * n], r1 = pos[2 * n + 1];
  float p0 = prob[2 * n], p1 = prob[2 * n + 1];
  uint4 a = *(const uint4*)&y[(size_t)r0 * DDIM + d8 * 8];
  uint4 b = *(const uint4*)&y[(size_t)r1 * DDIM + d8 * 8];
  const unsigned short* ah = (const unsigned short*)&a;
  const unsigned short* bh = (const unsigned short*)&b;
  float o[8];
#pragma unroll
  for (int k = 0; k < 8; k++) {
    float fa = __uint_as_float((unsigned)ah[k] << 16);
    float fb = __uint_as_float((unsigned)bh[k] << 16);
    o[k] = p0 * fa + p1 * fb;
  }
  float4* op = (float4*)&out[(size_t)n * DDIM + d8 * 8];
  op[0] = (float4){o[0], o[1], o[2], o[3]};
  op[1] = (float4){o[4], o[5], o[6], o[7]};
  if (gid == 0) out[(size_t)N_TOK * DDIM] = 0.f;   // total_loss
}

extern "C" void kernel_launch(void* const* d_in, const int* in_sizes, int n_in,
                              void* d_out, int out_size, void* d_ws, size_t ws_size,
                              hipStream_t stream) {
  const float* x    = (const float*)d_in[0];
  const float* prob = (const float*)d_in[1];
  const int*   idx  = (const int*)d_in[2];
  const float* W1   = (const float*)d_in[3];
  const float* b1   = (const float*)d_in[4];
  const float* W2   = (const float*)d_in[5];
  const float* b2   = (const float*)d_in[6];
  float* out = (float*)d_out;
  int stride = (in_sizes[2] == NK) ? 1 : 2;   // int32 vs int64 (LE low word)

  char* ws = (char*)d_ws;
  size_t cur = 0;
  auto alloc = [&](size_t bytes) -> void* {
    cur = (cur + 255) & ~(size_t)255;
    void* p = ws + cur; cur += bytes; return p;
  };
  int* offp  = (int*)alloc((NEXP + 1) * 4);
  int* texp  = (int*)alloc(MAXT * 4);
  int* tok   = (int*)alloc((size_t)MAXT * BM * 4);
  int* pos   = (int*)alloc((size_t)NK * 4);
  bf16* Xb   = (bf16*)alloc((size_t)N_TOK * DDIM * 2);
  bf16* W1t  = (bf16*)alloc((size_t)NEXP * HDIM * DDIM * 2);
  bf16* W2t  = (bf16*)alloc((size_t)NEXP * DDIM * HDIM * 2);
  bf16* ybuf = (bf16*)alloc((size_t)MAXT * BM * DDIM * 2);
  cur = (cur + 255) & ~(size_t)255;
  size_t h_off = cur;
  size_t h_avail = ws_size > h_off ? ws_size - h_off : 0;
  long long ts_ll = (long long)(h_avail / ((size_t)BM * HDIM * 2));
  int ts = (int)(ts_ll < 1 ? 1 : (ts_ll > MAXT ? MAXT : ts_ll));
  bf16* hbuf = (bf16*)(ws + h_off);

  k_router<<<1, 1024, 0, stream>>>(idx, stride, offp, texp, tok, pos);
  k_cvt_x<<<(N_TOK * DDIM / 8 + 255) / 256, 256, 0, stream>>>(x, Xb);
  k_transpose<<<dim3(HDIM / 64, DDIM / 32, NEXP), 256, 0, stream>>>(W1, W1t, DDIM, HDIM);
  k_transpose<<<dim3(DDIM / 64, HDIM / 32, NEXP), 256, 0, stream>>>(W2, W2t, HDIM, DDIM);

  for (int base = 0; base < MAXT; base += ts) {
    int cnt_t = (MAXT - base < ts) ? (MAXT - base) : ts;
    k_gemm<0><<<dim3(cnt_t * (HDIM / 256)), 512, 0, stream>>>(
        Xb, W1t, b1, texp, tok, base, (void*)hbuf);
    k_gemm<1><<<dim3(cnt_t * (DDIM / 256)), 512, 0, stream>>>(
        hbuf, W2t, b2, texp, tok, base, (void*)ybuf);
  }
  k_combine<<<(N_TOK * DDIM / 8 + 255) / 256, 256, 0, stream>>>(ybuf, prob, pos, out);
}

// Round 15
// 482.947 us; speedup vs baseline: 1.0135x; 1.0135x over previous
//
#include <hip/hip_runtime.h>
#include <hip/hip_bf16.h>

#define N_TOK 8192
#define DDIM 1024
#define HDIM 4096
#define NEXP 8
#define TOPK 2
#define NK (N_TOK*TOPK)
#define BM 128
#define BK 32
#define MAXT 136   // 16384/128 + 8 pad tiles

typedef __hip_bfloat16 bf16;
typedef __attribute__((ext_vector_type(8))) short bf16x8;
typedef __attribute__((ext_vector_type(4))) float f32x4;

__device__ __forceinline__ void gload16(const void* g, void* lds) {
  auto l = (__attribute__((address_space(3))) unsigned int*)(unsigned int)(unsigned long long)lds;
  auto gg = (const __attribute__((address_space(1))) unsigned int*)(unsigned long long)g;
  __builtin_amdgcn_global_load_lds(gg, l, 16, 0, 0);
}

// ---- fused router: count + padded scan + scatter + pad-fill, one block ----
__global__ void k_router(const int* __restrict__ idx, int stride,
                         int* __restrict__ offp, int* __restrict__ texp,
                         int* __restrict__ tok, int* __restrict__ pos) {
  __shared__ int cnt[NEXP], so[NEXP + 1], off2[NEXP], scnt[NEXP];
  int tid = threadIdx.x;
  if (tid < NEXP) cnt[tid] = 0;
  __syncthreads();
  for (int r = tid; r < NK; r += blockDim.x) {
    int e = idx[r * stride];
    e = min(max(e, 0), NEXP - 1);
    atomicAdd(&cnt[e], 1);
  }
  __syncthreads();
  if (tid == 0) {
    int cum = 0;
    for (int e = 0; e < NEXP; e++) {
      so[e] = cum;
      cum += ((cnt[e] + BM - 1) / BM) * BM;
    }
    so[NEXP] = cum;
    for (int e = 0; e <= NEXP; e++) offp[e] = so[e];
  }
  __syncthreads();
  if (tid < NEXP) { off2[tid] = so[tid]; scnt[tid] = cnt[tid]; }
  __syncthreads();
  for (int r = tid; r < NK; r += blockDim.x) {
    int e = idx[r * stride];
    e = min(max(e, 0), NEXP - 1);
    int p = atomicAdd(&off2[e], 1);
    tok[p] = r >> 1;
    pos[r] = p;
  }
  int total_tiles = so[NEXP] / BM;
  for (int t = tid; t < MAXT; t += blockDim.x) {
    int e = -1;
    if (t < total_tiles) {
      for (int q = 0; q < NEXP; q++)
        if (t * BM >= so[q] && t * BM < so[q + 1]) e = q;
    }
    texp[t] = e;
  }
  for (int e = 0; e < NEXP; e++) {
    int start = so[e] + scnt[e], end = so[e + 1];
    for (int i = start + tid; i < end; i += blockDim.x) tok[i] = 0;
  }
}

// ---- fp32 -> bf16 convert of X ----
__global__ void k_cvt_x(const float* __restrict__ x, bf16* __restrict__ xb) {
  int i = blockIdx.x * blockDim.x + threadIdx.x;   // over N*D/8
  if (i >= N_TOK * DDIM / 8) return;
  float4 a = ((const float4*)x)[(size_t)i * 2];
  float4 b = ((const float4*)x)[(size_t)i * 2 + 1];
  union { bf16 h[8]; uint4 v; } u;
  u.h[0] = __float2bfloat16(a.x); u.h[1] = __float2bfloat16(a.y);
  u.h[2] = __float2bfloat16(a.z); u.h[3] = __float2bfloat16(a.w);
  u.h[4] = __float2bfloat16(b.x); u.h[5] = __float2bfloat16(b.y);
  u.h[6] = __float2bfloat16(b.z); u.h[7] = __float2bfloat16(b.w);
  *(uint4*)&xb[(size_t)i * 8] = u.v;
}

// [E][R][C] fp32 -> [E][C][R] bf16. Tile 32R x 64C; 16B stores.
__global__ void k_transpose(const float* __restrict__ in, bf16* __restrict__ out,
                            int R, int C) {
  __shared__ float t[32][65];
  size_t ebase = (size_t)blockIdx.z * R * C;
  int r0 = blockIdx.y * 32, c0 = blockIdx.x * 64;
  int tid = threadIdx.x;
  {
    int lr = tid >> 3, lc = (tid & 7) * 8;
    const float4* src = (const float4*)&in[ebase + (size_t)(r0 + lr) * C + c0 + lc];
    float4 a = src[0], b = src[1];
    t[lr][lc + 0] = a.x; t[lr][lc + 1] = a.y; t[lr][lc + 2] = a.z; t[lr][lc + 3] = a.w;
    t[lr][lc + 4] = b.x; t[lr][lc + 5] = b.y; t[lr][lc + 6] = b.z; t[lr][lc + 7] = b.w;
  }
  __syncthreads();
  {
    int sc = tid >> 2, sr = (tid & 3) * 8;
    union { bf16 h[8]; uint4 v; } u;
#pragma unroll
    for (int j = 0; j < 8; j++) u.h[j] = __float2bfloat16(t[sr + j][sc]);
    *(uint4*)&out[ebase + (size_t)(c0 + sc) * R + r0 + sr] = u.v;
  }
}

// ---- grouped GEMM: 128x256 tile, BK=32, 4 waves (2Mx2N, 64x128/wave),
//      3-buffer LDS (72 KB -> 2 blocks/CU), counted vmcnt(6), 1 barrier/step.
//      R12 schedule; fatter waves cut LDS-port frag reads 25%. ----
// MODE 0: Xb(gathered via tok) @ W1t -> hbuf bf16 (+bias, ReLU), slice rows.
// MODE 1: hbuf @ W2t -> ybuf bf16 (+bias), global rows.
template<int MODE>
__global__ __launch_bounds__(256, 2) void k_gemm(
    const bf16* __restrict__ A, const bf16* __restrict__ Bt,
    const float* __restrict__ bias, const int* __restrict__ texp,
    const int* __restrict__ tok, int tile_base, void* __restrict__ Cout)
{
  constexpr int KT   = MODE ? HDIM : DDIM;   // 4096 : 1024
  constexpr int NCOL = MODE ? DDIM : HDIM;
  constexpr int BN   = 256;
  constexpr int GX   = NCOL / BN;            // 4 : 16
  constexpr int NT   = KT / BK;              // 128 : 32
  constexpr int BUFB = (BM + BN) * BK * 2;   // 24 KB per buffer

  // bijective XCD-aware swizzle (m204)
  int nwg = gridDim.x, orig = blockIdx.x;
  int q8 = nwg >> 3, r8 = nwg & 7;
  int xcd = orig & 7, jj0 = orig >> 3;
  int w = (xcd < r8 ? xcd * (q8 + 1) : r8 * (q8 + 1) + (xcd - r8) * q8) + jj0;
  int tn = w % GX;
  int tmr = w / GX;
  int tm = tile_base + tmr;
  int e = texp[tm];
  if (e < 0) return;

  int tid = threadIdx.x, lane = tid & 63, wid = tid >> 6;
  int wm = wid >> 1, wn = wid & 1;           // 2M x 2N waves, 64x128 each
  int lr = lane & 15, kg = lane >> 4;

  __shared__ __align__(16) char lds[3 * BUFB];   // 72 KiB

  // staging source offsets (elements); source chunk swizzle c ^= (row>>1)&3
  // chunks: 0..511 A (128 rows x 4), 512..1535 B (256 rows x 4); 6 loads/thread.
  unsigned goff[6];
#pragma unroll
  for (int it = 0; it < 6; ++it) {
    int idx = it * 256 + tid;
    if (it < 2) {
      int row = idx >> 2, c = idx & 3;
      int ch = c ^ ((row >> 1) & 3);
      int arow = MODE ? (tmr * BM + row) : tok[tm * BM + row];
      goff[it] = (unsigned)(arow * KT + ch * 8);
    } else {
      int bi = idx - 512, row = bi >> 2, c = bi & 3;
      int ch = c ^ ((row >> 1) & 3);
      goff[it] = (unsigned)((e * NCOL + tn * BN + row) * KT + ch * 8);
    }
  }

  auto stage = [&](int kt, int buf) {
    char* base = lds + buf * BUFB;
#pragma unroll
    for (int it = 0; it < 2; ++it)
      gload16(A + goff[it] + kt * BK, base + (it * 256 + tid) * 16);
#pragma unroll
    for (int it = 2; it < 6; ++it)
      gload16(Bt + goff[it] + kt * BK, base + 8192 + ((it - 2) * 256 + tid) * 16);
  };

  f32x4 acc[4][8];
#pragma unroll
  for (int i = 0; i < 4; i++)
#pragma unroll
    for (int j = 0; j < 8; j++) acc[i][j] = (f32x4){0.f, 0.f, 0.f, 0.f};

  // prologue: tiles 0,1 in flight; vmcnt(6) publishes tile 0
  stage(0, 0);
  stage(1, 1);
  asm volatile("s_waitcnt vmcnt(6)" ::: "memory");
  __builtin_amdgcn_s_barrier();

#pragma unroll 1
  for (int kt = 0; kt < NT; ++kt) {
    if (kt + 2 < NT) stage(kt + 2, (kt + 2) % 3);   // buf of tile kt-1: reads done

    const char* base = lds + (kt % 3) * BUFB;
    bf16x8 av[4], bv[8];
#pragma unroll
    for (int mi = 0; mi < 4; ++mi) {
      int m = wm * 64 + mi * 16 + lr;
      int slot = kg ^ ((m >> 1) & 3);
      av[mi] = *(const bf16x8*)(base + m * 64 + slot * 16);
    }
#pragma unroll
    for (int ni = 0; ni < 8; ++ni) {
      int n = wn * 128 + ni * 16 + lr;
      int slot = kg ^ ((n >> 1) & 3);
      bv[ni] = *(const bf16x8*)(base + 8192 + n * 64 + slot * 16);
    }

#pragma unroll
    for (int mi = 0; mi < 4; ++mi)
#pragma unroll
      for (int ni = 0; ni < 8; ++ni)
        acc[mi][ni] = __builtin_amdgcn_mfma_f32_16x16x32_bf16(
            av[mi], bv[ni], acc[mi][ni], 0, 0, 0);

    if (kt + 1 < NT) {
      if (kt + 2 < NT) asm volatile("s_waitcnt vmcnt(6)" ::: "memory"); // kt+1 landed, kt+2 in flight
      else             asm volatile("s_waitcnt vmcnt(0)" ::: "memory");
      __builtin_amdgcn_s_barrier();
    }
  }

  // epilogue (C/D map m89)
  const float* be = bias + (size_t)e * NCOL;
  int crow0 = (MODE ? tm : tmr) * BM;
#pragma unroll
  for (int ni = 0; ni < 8; ++ni) {
    int n = tn * BN + wn * 128 + ni * 16 + lr;
    float bvv = be[n];
#pragma unroll
    for (int mi = 0; mi < 4; ++mi) {
#pragma unroll
      for (int j = 0; j < 4; j++) {
        int mrow = wm * 64 + mi * 16 + kg * 4 + j;
        float v = acc[mi][ni][j] + bvv;
        if (MODE == 0) v = fmaxf(v, 0.f);
        ((bf16*)Cout)[(size_t)(crow0 + mrow) * NCOL + n] = __float2bfloat16(v);
      }
    }
  }
}

// ---- combine (bf16 y) ----
__global__ void k_combine(const bf16* __restrict__ y, const float* __restrict__ prob,
                          const int* __restrict__ pos, float* __restrict__ out) {
  int gid = blockIdx.x * blockDim.x + threadIdx.x;  // over N*D/8
  if (gid >= N_TOK * DDIM / 8) return;
  int n = gid >> 7;          // DDIM/8 = 128
  int d8 = gid & 127;
  int r0 = pos[2 * n], r1 = pos[2 * n + 1];
  float p0 = prob[2 * n], p1 = prob[2 * n + 1];
  uint4 a = *(const uint4*)&y[(size_t)r0 * DDIM + d8 * 8];
  uint4 b = *(const uint4*)&y[(size_t)r1 * DDIM + d8 * 8];
  const unsigned short* ah = (const unsigned short*)&a;
  const unsigned short* bh = (const unsigned short*)&b;
  float o[8];
#pragma unroll
  for (int k = 0; k < 8; k++) {
    float fa = __uint_as_float((unsigned)ah[k] << 16);
    float fb = __uint_as_float((unsigned)bh[k] << 16);
    o[k] = p0 * fa + p1 * fb;
  }
  float4* op = (float4*)&out[(size_t)n * DDIM + d8 * 8];
  op[0] = (float4){o[0], o[1], o[2], o[3]};
  op[1] = (float4){o[4], o[5], o[6], o[7]};
  if (gid == 0) out[(size_t)N_TOK * DDIM] = 0.f;   // total_loss
}

extern "C" void kernel_launch(void* const* d_in, const int* in_sizes, int n_in,
                              void* d_out, int out_size, void* d_ws, size_t ws_size,
                              hipStream_t stream) {
  const float* x    = (const float*)d_in[0];
  const float* prob = (const float*)d_in[1];
  const int*   idx  = (const int*)d_in[2];
  const float* W1   = (const float*)d_in[3];
  const float* b1   = (const float*)d_in[4];
  const float* W2   = (const float*)d_in[5];
  const float* b2   = (const float*)d_in[6];
  float* out = (float*)d_out;
  int stride = (in_sizes[2] == NK) ? 1 : 2;   // int32 vs int64 (LE low word)

  char* ws = (char*)d_ws;
  size_t cur = 0;
  auto alloc = [&](size_t bytes) -> void* {
    cur = (cur + 255) & ~(size_t)255;
    void* p = ws + cur; cur += bytes; return p;
  };
  int* offp  = (int*)alloc((NEXP + 1) * 4);
  int* texp  = (int*)alloc(MAXT * 4);
  int* tok   = (int*)alloc((size_t)MAXT * BM * 4);
  int* pos   = (int*)alloc((size_t)NK * 4);
  bf16* Xb   = (bf16*)alloc((size_t)N_TOK * DDIM * 2);
  bf16* W1t  = (bf16*)alloc((size_t)NEXP * HDIM * DDIM * 2);
  bf16* W2t  = (bf16*)alloc((size_t)NEXP * DDIM * HDIM * 2);
  bf16* ybuf = (bf16*)alloc((size_t)MAXT * BM * DDIM * 2);
  cur = (cur + 255) & ~(size_t)255;
  size_t h_off = cur;
  size_t h_avail = ws_size > h_off ? ws_size - h_off : 0;
  long long ts_ll = (long long)(h_avail / ((size_t)BM * HDIM * 2));
  int ts = (int)(ts_ll < 1 ? 1 : (ts_ll > MAXT ? MAXT : ts_ll));
  bf16* hbuf = (bf16*)(ws + h_off);

  k_router<<<1, 1024, 0, stream>>>(idx, stride, offp, texp, tok, pos);
  k_cvt_x<<<(N_TOK * DDIM / 8 + 255) / 256, 256, 0, stream>>>(x, Xb);
  k_transpose<<<dim3(HDIM / 64, DDIM / 32, NEXP), 256, 0, stream>>>(W1, W1t, DDIM, HDIM);
  k_transpose<<<dim3(DDIM / 64, HDIM / 32, NEXP), 256, 0, stream>>>(W2, W2t, HDIM, DDIM);

  for (int base = 0; base < MAXT; base += ts) {
    int cnt_t = (MAXT - base < ts) ? (MAXT - base) : ts;
    k_gemm<0><<<dim3(cnt_t * (HDIM / 256)), 256, 0, stream>>>(
        Xb, W1t, b1, texp, tok, base, (void*)hbuf);
    k_gemm<1><<<dim3(cnt_t * (DDIM / 256)), 256, 0, stream>>>(
        hbuf, W2t, b2, texp, tok, base, (void*)ybuf);
  }
  k_combine<<<(N_TOK * DDIM / 8 + 255) / 256, 256, 0, stream>>>(ybuf, prob, pos, out);
}

// Round 16
// 470.783 us; speedup vs baseline: 1.0397x; 1.0258x over previous
//
#include <hip/hip_runtime.h>
#include <hip/hip_bf16.h>

#define N_TOK 8192
#define DDIM 1024
#define HDIM 4096
#define NEXP 8
#define TOPK 2
#define NK (N_TOK*TOPK)
#define BM 128
#define BK 32
#define MAXT 136   // 16384/128 + 8 pad tiles

typedef __hip_bfloat16 bf16;
typedef __attribute__((ext_vector_type(8))) short bf16x8;
typedef __attribute__((ext_vector_type(4))) float f32x4;

__device__ __forceinline__ void gload16(const void* g, void* lds) {
  auto l = (__attribute__((address_space(3))) unsigned int*)(unsigned int)(unsigned long long)lds;
  auto gg = (const __attribute__((address_space(1))) unsigned int*)(unsigned long long)g;
  __builtin_amdgcn_global_load_lds(gg, l, 16, 0, 0);
}

// ---- fused router: count + padded scan + scatter + pad-fill, one block ----
__global__ void k_router(const int* __restrict__ idx, int stride,
                         int* __restrict__ offp, int* __restrict__ texp,
                         int* __restrict__ tok, int* __restrict__ pos) {
  __shared__ int cnt[NEXP], so[NEXP + 1], off2[NEXP], scnt[NEXP];
  int tid = threadIdx.x;
  if (tid < NEXP) cnt[tid] = 0;
  __syncthreads();
  for (int r = tid; r < NK; r += blockDim.x) {
    int e = idx[r * stride];
    e = min(max(e, 0), NEXP - 1);
    atomicAdd(&cnt[e], 1);
  }
  __syncthreads();
  if (tid == 0) {
    int cum = 0;
    for (int e = 0; e < NEXP; e++) {
      so[e] = cum;
      cum += ((cnt[e] + BM - 1) / BM) * BM;
    }
    so[NEXP] = cum;
    for (int e = 0; e <= NEXP; e++) offp[e] = so[e];
  }
  __syncthreads();
  if (tid < NEXP) { off2[tid] = so[tid]; scnt[tid] = cnt[tid]; }
  __syncthreads();
  for (int r = tid; r < NK; r += blockDim.x) {
    int e = idx[r * stride];
    e = min(max(e, 0), NEXP - 1);
    int p = atomicAdd(&off2[e], 1);
    tok[p] = r >> 1;
    pos[r] = p;
  }
  int total_tiles = so[NEXP] / BM;
  for (int t = tid; t < MAXT; t += blockDim.x) {
    int e = -1;
    if (t < total_tiles) {
      for (int q = 0; q < NEXP; q++)
        if (t * BM >= so[q] && t * BM < so[q + 1]) e = q;
    }
    texp[t] = e;
  }
  for (int e = 0; e < NEXP; e++) {
    int start = so[e] + scnt[e], end = so[e + 1];
    for (int i = start + tid; i < end; i += blockDim.x) tok[i] = 0;
  }
}

// ---- fp32 -> bf16 convert of X ----
__global__ void k_cvt_x(const float* __restrict__ x, bf16* __restrict__ xb) {
  int i = blockIdx.x * blockDim.x + threadIdx.x;   // over N*D/8
  if (i >= N_TOK * DDIM / 8) return;
  float4 a = ((const float4*)x)[(size_t)i * 2];
  float4 b = ((const float4*)x)[(size_t)i * 2 + 1];
  union { bf16 h[8]; uint4 v; } u;
  u.h[0] = __float2bfloat16(a.x); u.h[1] = __float2bfloat16(a.y);
  u.h[2] = __float2bfloat16(a.z); u.h[3] = __float2bfloat16(a.w);
  u.h[4] = __float2bfloat16(b.x); u.h[5] = __float2bfloat16(b.y);
  u.h[6] = __float2bfloat16(b.z); u.h[7] = __float2bfloat16(b.w);
  *(uint4*)&xb[(size_t)i * 8] = u.v;
}

// [E][R][C] fp32 -> [E][C][R] bf16. Tile 32R x 64C; 16B stores.
__global__ void k_transpose(const float* __restrict__ in, bf16* __restrict__ out,
                            int R, int C) {
  __shared__ float t[32][65];
  size_t ebase = (size_t)blockIdx.z * R * C;
  int r0 = blockIdx.y * 32, c0 = blockIdx.x * 64;
  int tid = threadIdx.x;
  {
    int lr = tid >> 3, lc = (tid & 7) * 8;
    const float4* src = (const float4*)&in[ebase + (size_t)(r0 + lr) * C + c0 + lc];
    float4 a = src[0], b = src[1];
    t[lr][lc + 0] = a.x; t[lr][lc + 1] = a.y; t[lr][lc + 2] = a.z; t[lr][lc + 3] = a.w;
    t[lr][lc + 4] = b.x; t[lr][lc + 5] = b.y; t[lr][lc + 6] = b.z; t[lr][lc + 7] = b.w;
  }
  __syncthreads();
  {
    int sc = tid >> 2, sr = (tid & 3) * 8;
    union { bf16 h[8]; uint4 v; } u;
#pragma unroll
    for (int j = 0; j < 8; j++) u.h[j] = __float2bfloat16(t[sr + j][sc]);
    *(uint4*)&out[ebase + (size_t)(c0 + sc) * R + r0 + sr] = u.v;
  }
}

// ---- grouped GEMM: 128x256 tile, BK=32, 8 waves (2Mx4N, 64x64/wave),
//      3-buffer LDS (72 KB), counted vmcnt(3), 1 barrier/step (R12-verified) ----
// MODE 0: Xb(gathered via tok) @ W1t -> hbuf bf16 (+bias, ReLU), slice rows.
// MODE 1: hbuf @ W2t -> ybuf bf16 (+bias), global rows.
template<int MODE>
__global__ __launch_bounds__(512, 4) void k_gemm(
    const bf16* __restrict__ A, const bf16* __restrict__ Bt,
    const float* __restrict__ bias, const int* __restrict__ texp,
    const int* __restrict__ tok, int tile_base, void* __restrict__ Cout)
{
  constexpr int KT   = MODE ? HDIM : DDIM;   // 4096 : 1024
  constexpr int NCOL = MODE ? DDIM : HDIM;
  constexpr int BN   = 256;
  constexpr int GX   = NCOL / BN;            // 4 : 16
  constexpr int NT   = KT / BK;              // 128 : 32
  constexpr int BUFB = (BM + BN) * BK * 2;   // 24 KB per buffer

  // bijective XCD-aware swizzle (m204)
  int nwg = gridDim.x, orig = blockIdx.x;
  int q8 = nwg >> 3, r8 = nwg & 7;
  int xcd = orig & 7, jj0 = orig >> 3;
  int w = (xcd < r8 ? xcd * (q8 + 1) : r8 * (q8 + 1) + (xcd - r8) * q8) + jj0;
  int tn = w % GX;
  int tmr = w / GX;
  int tm = tile_base + tmr;
  int e = texp[tm];
  if (e < 0) return;

  int tid = threadIdx.x, lane = tid & 63, wid = tid >> 6;
  int wm = wid >> 2, wn = wid & 3;           // 2M x 4N waves, 64x64 each
  int lr = lane & 15, kg = lane >> 4;

  __shared__ __align__(16) char lds[3 * BUFB];   // 72 KiB

  // staging source offsets (elements); source chunk swizzle c ^= (row>>1)&3
  unsigned goff[3];
  {
    int row = tid >> 2, c = tid & 3;
    int ch = c ^ ((row >> 1) & 3);
    int arow = MODE ? (tmr * BM + row) : tok[tm * BM + row];
    goff[0] = (unsigned)(arow * KT + ch * 8);
    goff[1] = (unsigned)((e * NCOL + tn * BN + row) * KT + ch * 8);
    goff[2] = (unsigned)((e * NCOL + tn * BN + 128 + row) * KT + ch * 8);
  }

  auto stage = [&](int kt, int buf) {
    char* base = lds + buf * BUFB;
    gload16(A + goff[0] + kt * BK, base + tid * 16);
    gload16(Bt + goff[1] + kt * BK, base + 8192 + tid * 16);
    gload16(Bt + goff[2] + kt * BK, base + 16384 + tid * 16);
  };

  f32x4 acc[4][4];
#pragma unroll
  for (int i = 0; i < 4; i++)
#pragma unroll
    for (int j = 0; j < 4; j++) acc[i][j] = (f32x4){0.f, 0.f, 0.f, 0.f};

  // prologue: tiles 0,1 in flight; publish tile 0
  stage(0, 0);
  stage(1, 1);
  asm volatile("s_waitcnt vmcnt(3)" ::: "memory");
  __builtin_amdgcn_s_barrier();

#pragma unroll 1
  for (int kt = 0; kt < NT; ++kt) {
    if (kt + 2 < NT) stage(kt + 2, (kt + 2) % 3);   // buf of tile kt-1: reads done

    const char* base = lds + (kt % 3) * BUFB;
    bf16x8 av[4], bv[4];
#pragma unroll
    for (int mi = 0; mi < 4; ++mi) {
      int m = wm * 64 + mi * 16 + lr;
      int slot = kg ^ ((m >> 1) & 3);
      av[mi] = *(const bf16x8*)(base + m * 64 + slot * 16);
    }
#pragma unroll
    for (int ni = 0; ni < 4; ++ni) {
      int n = wn * 64 + ni * 16 + lr;
      int slot = kg ^ ((n >> 1) & 3);
      bv[ni] = *(const bf16x8*)(base + 8192 + n * 64 + slot * 16);
    }

#pragma unroll
    for (int mi = 0; mi < 4; ++mi)
#pragma unroll
      for (int ni = 0; ni < 4; ++ni)
        acc[mi][ni] = __builtin_amdgcn_mfma_f32_16x16x32_bf16(
            av[mi], bv[ni], acc[mi][ni], 0, 0, 0);

    if (kt + 1 < NT) {
      if (kt + 2 < NT) asm volatile("s_waitcnt vmcnt(3)" ::: "memory"); // kt+1 landed, kt+2 in flight
      else             asm volatile("s_waitcnt vmcnt(0)" ::: "memory");
      __builtin_amdgcn_s_barrier();
    }
  }

  // epilogue (C/D map m89)
  const float* be = bias + (size_t)e * NCOL;
  int crow0 = (MODE ? tm : tmr) * BM;
#pragma unroll
  for (int ni = 0; ni < 4; ++ni) {
    int n = tn * BN + wn * 64 + ni * 16 + lr;
    float bvv = be[n];
#pragma unroll
    for (int mi = 0; mi < 4; ++mi) {
#pragma unroll
      for (int j = 0; j < 4; j++) {
        int mrow = wm * 64 + mi * 16 + kg * 4 + j;
        float v = acc[mi][ni][j] + bvv;
        if (MODE == 0) v = fmaxf(v, 0.f);
        ((bf16*)Cout)[(size_t)(crow0 + mrow) * NCOL + n] = __float2bfloat16(v);
      }
    }
  }
}

// ---- combine (bf16 y) ----
__global__ void k_combine(const bf16* __restrict__ y, const float* __restrict__ prob,
                          const int* __restrict__ pos, float* __restrict__ out) {
  int gid = blockIdx.x * blockDim.x + threadIdx.x;  // over N*D/8
  if (gid >= N_TOK * DDIM / 8) return;
  int n = gid >> 7;          // DDIM/8 = 128
  int d8 = gid & 127;
  int r0 = pos[2 * n], r1 = pos[2 * n + 1];
  float p0 = prob[2 * n], p1 = prob[2 * n + 1];
  uint4 a = *(const uint4*)&y[(size_t)r0 * DDIM + d8 * 8];
  uint4 b = *(const uint4*)&y[(size_t)r1 * DDIM + d8 * 8];
  const unsigned short* ah = (const unsigned short*)&a;
  const unsigned short* bh = (const unsigned short*)&b;
  float o[8];
#pragma unroll
  for (int k = 0; k < 8; k++) {
    float fa = __uint_as_float((unsigned)ah[k] << 16);
    float fb = __uint_as_float((unsigned)bh[k] << 16);
    o[k] = p0 * fa + p1 * fb;
  }
  float4* op = (float4*)&out[(size_t)n * DDIM + d8 * 8];
  op[0] = (float4){o[0], o[1], o[2], o[3]};
  op[1] = (float4){o[4], o[5], o[6], o[7]};
  if (gid == 0) out[(size_t)N_TOK * DDIM] = 0.f;   // total_loss
}

extern "C" void kernel_launch(void* const* d_in, const int* in_sizes, int n_in,
                              void* d_out, int out_size, void* d_ws, size_t ws_size,
                              hipStream_t stream) {
  const float* x    = (const float*)d_in[0];
  const float* prob = (const float*)d_in[1];
  const int*   idx  = (const int*)d_in[2];
  const float* W1   = (const float*)d_in[3];
  const float* b1   = (const float*)d_in[4];
  const float* W2   = (const float*)d_in[5];
  const float* b2   = (const float*)d_in[6];
  float* out = (float*)d_out;
  int stride = (in_sizes[2] == NK) ? 1 : 2;   // int32 vs int64 (LE low word)

  char* ws = (char*)d_ws;
  size_t cur = 0;
  auto alloc = [&](size_t bytes) -> void* {
    cur = (cur + 255) & ~(size_t)255;
    void* p = ws + cur; cur += bytes; return p;
  };
  int* offp  = (int*)alloc((NEXP + 1) * 4);
  int* texp  = (int*)alloc(MAXT * 4);
  int* tok   = (int*)alloc((size_t)MAXT * BM * 4);
  int* pos   = (int*)alloc((size_t)NK * 4);
  bf16* Xb   = (bf16*)alloc((size_t)N_TOK * DDIM * 2);
  bf16* W1t  = (bf16*)alloc((size_t)NEXP * HDIM * DDIM * 2);
  bf16* W2t  = (bf16*)alloc((size_t)NEXP * DDIM * HDIM * 2);
  bf16* ybuf = (bf16*)alloc((size_t)MAXT * BM * DDIM * 2);
  cur = (cur + 255) & ~(size_t)255;
  size_t h_off = cur;
  size_t h_avail = ws_size > h_off ? ws_size - h_off : 0;
  long long ts_ll = (long long)(h_avail / ((size_t)BM * HDIM * 2));
  int ts = (int)(ts_ll < 1 ? 1 : (ts_ll > MAXT ? MAXT : ts_ll));
  bf16* hbuf = (bf16*)(ws + h_off);

  k_router<<<1, 1024, 0, stream>>>(idx, stride, offp, texp, tok, pos);
  k_cvt_x<<<(N_TOK * DDIM / 8 + 255) / 256, 256, 0, stream>>>(x, Xb);
  k_transpose<<<dim3(HDIM / 64, DDIM / 32, NEXP), 256, 0, stream>>>(W1, W1t, DDIM, HDIM);
  k_transpose<<<dim3(DDIM / 64, HDIM / 32, NEXP), 256, 0, stream>>>(W2, W2t, HDIM, DDIM);

  for (int base = 0; base < MAXT; base += ts) {
    int cnt_t = (MAXT - base < ts) ? (MAXT - base) : ts;
    k_gemm<0><<<dim3(cnt_t * (HDIM / 256)), 512, 0, stream>>>(
        Xb, W1t, b1, texp, tok, base, (void*)hbuf);
    k_gemm<1><<<dim3(cnt_t * (DDIM / 256)), 512, 0, stream>>>(
        hbuf, W2t, b2, texp, tok, base, (void*)ybuf);
  }
  k_combine<<<(N_TOK * DDIM / 8 + 255) / 256, 256, 0, stream>>>(ybuf, prob, pos, out);
}